// Round 6
// baseline (263.197 us; speedup 1.0000x reference)
//
#include <hip/hip_runtime.h>

// AvgSeq: out[b,s,d] = (sum_{t<=s} x[b,t,d]) / (s+1)
// x: [16, 8192, 256] float32
//
// Two-pass chunked scan, NC=256 (4096 single-wave blocks = 16 waves/CU):
//   K1: chunk sums -> ws       (one wave per (b,chunk), lane = float4 column)
//   K2: prefix over preceding chunk sums (8-deep MLP windows, L2-resident),
//       then software-pipelined scan of own 32-row chunk: 2 named 8-wide
//       load batches in flight, nontemporal stores (out never re-read,
//       keeps x resident in L3 for the re-read).
#define BB 16
#define SS 8192
#define DD 256
#define D4 (DD / 4)     // 64 float4 columns; one wave covers all of D
#define NC 256          // chunks along S
#define CL (SS / NC)    // 32 rows per chunk
#define G  16           // K1 load-batch width
#define H  8            // K2 load-batch width (keeps VGPR low -> occupancy)

typedef float nat4 __attribute__((ext_vector_type(4)));

__global__ __launch_bounds__(64) void avgseq_chunksum(const float4* __restrict__ x,
                                                      float4* __restrict__ ws) {
    const int blk = blockIdx.x;          // b*NC + c
    const int b = blk >> 8;              // / NC
    const int c = blk & (NC - 1);
    const int t = threadIdx.x;           // float4 column

    const float4* p = x + ((size_t)b * SS + (size_t)c * CL) * D4 + t;
    float4 acc = make_float4(0.f, 0.f, 0.f, 0.f);
    for (int s0 = 0; s0 < CL; s0 += G) {
        float4 v[G];
#pragma unroll
        for (int g = 0; g < G; ++g) v[g] = p[(size_t)(s0 + g) * D4];
#pragma unroll
        for (int g = 0; g < G; ++g) {
            acc.x += v[g].x; acc.y += v[g].y; acc.z += v[g].z; acc.w += v[g].w;
        }
    }
    ws[((size_t)b * NC + c) * D4 + t] = acc;
}

__global__ __launch_bounds__(64) void avgseq_scan(const float4* __restrict__ x,
                                                  const float4* __restrict__ ws,
                                                  float4* __restrict__ out) {
    const int blk = blockIdx.x;          // b*NC + c
    const int b = blk >> 8;
    const int c = blk & (NC - 1);
    const int t = threadIdx.x;

    // ---- prefix over chunk sums < c: 8-deep MLP windows (table is L2-resident) ----
    const float4* w = ws + (size_t)b * NC * D4 + t;
    float4 pre = make_float4(0.f, 0.f, 0.f, 0.f);
    int cc = 0;
    for (; cc + 8 <= c; cc += 8) {
        float4 a[8];
#pragma unroll
        for (int k = 0; k < 8; ++k) a[k] = w[(size_t)(cc + k) * D4];
#pragma unroll
        for (int k = 0; k < 8; ++k) {
            pre.x += a[k].x; pre.y += a[k].y; pre.z += a[k].z; pre.w += a[k].w;
        }
    }
    for (; cc < c; ++cc) {
        float4 v = w[(size_t)cc * D4];
        pre.x += v.x; pre.y += v.y; pre.z += v.z; pre.w += v.w;
    }

    const size_t base = ((size_t)b * SS + (size_t)c * CL) * D4 + t;
    const float4* p = x + base;
    float4* o = out + base;
    const int s0 = c * CL;
    float4 acc = pre;

    // ---- software-pipelined main scan: CL=32 rows = 4 named batches of H=8 ----
    float4 u0[H], u1[H];
#define LOADB(dst, off)                                                        \
    _Pragma("unroll")                                                          \
    for (int g = 0; g < H; ++g) dst[g] = p[(size_t)((off) + g) * D4];
#define COMPSTORE(src, off)                                                    \
    _Pragma("unroll")                                                          \
    for (int g = 0; g < H; ++g) {                                              \
        acc.x += src[g].x; acc.y += src[g].y;                                  \
        acc.z += src[g].z; acc.w += src[g].w;                                  \
        const float r = __builtin_amdgcn_rcpf((float)(s0 + (off) + g + 1));    \
        nat4 nv = { acc.x * r, acc.y * r, acc.z * r, acc.w * r };              \
        __builtin_nontemporal_store(nv, (nat4*)&o[(size_t)((off) + g) * D4]);  \
    }

    LOADB(u0, 0)
    LOADB(u1, H)            // 16 loads (16 KB) in flight
    COMPSTORE(u0, 0)        // waits only on first 8 loads
    LOADB(u0, 2 * H)
    COMPSTORE(u1, H)
    LOADB(u1, 3 * H)
    COMPSTORE(u0, 2 * H)
    COMPSTORE(u1, 3 * H)
#undef LOADB
#undef COMPSTORE
}

extern "C" void kernel_launch(void* const* d_in, const int* in_sizes, int n_in,
                              void* d_out, int out_size, void* d_ws, size_t ws_size,
                              hipStream_t stream) {
    const float4* x = (const float4*)d_in[0];
    float4* out = (float4*)d_out;
    float4* ws = (float4*)d_ws;          // BB*NC*D4 float4 = 4 MiB

    const int nblocks = BB * NC;         // 4096 single-wave blocks = 16 waves/CU
    avgseq_chunksum<<<nblocks, 64, 0, stream>>>(x, ws);
    avgseq_scan<<<nblocks, 64, 0, stream>>>(x, ws, out);
}